// Round 2
// baseline (453.496 us; speedup 1.0000x reference)
//
#include <hip/hip_runtime.h>
#include <stdint.h>

// MPS classifier forward, MI355X.
//   K1 : 127 blocks, round-1 basis T_pq = {C0,dC}_n1 @ {C0,dC}_n2 (bf16, parity layout)
//   K1b: 63x16 blocks, round-2 basis TT_t = T1_p @ T2_q  (batch-independent!)
//   K1c: Gram G[j2] = V V^T (16x16) over TT basis via MFMA
//   K2n: per (j2,b): coeffs c[16], n = sqrt(c^T G c), log n (telescoped r1+r2 logs)
//   K2s: special chain rounds 1+2 (64 blocks)
//   K2c: element-wise combine M0 = (sum_t c_t TT_t)/n, register-resident TT slice
//   R3,R4: pairwise rounds, 512-thread blocks (8 waves)
//   tail: R5..R8 + logits fused, one block per batch

typedef unsigned short u16;
typedef __attribute__((ext_vector_type(8))) short short8;
typedef __attribute__((ext_vector_type(4))) float f32x4;

#define HP 136  // LDS row stride in bf16: 272 B, 16B-aligned, 2-way-bank-free

__device__ __forceinline__ u16 f2b(float f) {
  uint32_t u = __builtin_bit_cast(uint32_t, f);
  u += 0x7FFFu + ((u >> 16) & 1u);
  return (u16)(u >> 16);
}
__device__ __forceinline__ float b2f(u16 b) {
  uint32_t u = ((uint32_t)b) << 16;
  return __builtin_bit_cast(float, u);
}

struct Acc8 { f32x4 t[2][4]; };

// 512-thread (8-wave) 128x128x128: wave tile 32x64. A: [m][k] LDS, B: [n][k] LDS.
__device__ __forceinline__ void mfma128_w8(const u16* Alds, const u16* Blds,
                                           Acc8& acc) {
  const int tid = threadIdx.x;
  const int wid = tid >> 6, lane = tid & 63;
  const int wm = (wid >> 1) * 32, wn = (wid & 1) * 64;
  const int l16 = lane & 15, quad = lane >> 4;
#pragma unroll
  for (int tm = 0; tm < 2; tm++)
#pragma unroll
    for (int tn = 0; tn < 4; tn++)
      acc.t[tm][tn] = (f32x4){0.f, 0.f, 0.f, 0.f};
#pragma unroll
  for (int kk = 0; kk < 128; kk += 32) {
    short8 af[2], bf[4];
#pragma unroll
    for (int t = 0; t < 2; t++)
      af[t] = *(const short8*)(Alds + (wm + t * 16 + l16) * HP + kk + quad * 8);
#pragma unroll
    for (int t = 0; t < 4; t++)
      bf[t] = *(const short8*)(Blds + (wn + t * 16 + l16) * HP + kk + quad * 8);
#pragma unroll
    for (int tm = 0; tm < 2; tm++)
#pragma unroll
      for (int tn = 0; tn < 4; tn++)
        acc.t[tm][tn] = __builtin_amdgcn_mfma_f32_16x16x32_bf16(
            af[tm], bf[tn], acc.t[tm][tn], 0, 0, 0);
  }
}

__device__ __forceinline__ float acc_sumsq8(const Acc8& acc) {
  float ss = 0.f;
#pragma unroll
  for (int tm = 0; tm < 2; tm++)
#pragma unroll
    for (int tn = 0; tn < 4; tn++)
#pragma unroll
      for (int i = 0; i < 4; i++) {
        float v = acc.t[tm][tn][i];
        ss += v * v;
      }
  return ss;
}

// C/D layout (m89): row = quad*4 + reg, col = lane&15 per 16x16 tile.
__device__ __forceinline__ void store_tile8(u16* out, const Acc8& acc, float scale,
                                            bool transposed) {
  const int tid = threadIdx.x;
  const int wid = tid >> 6, lane = tid & 63;
  const int wm = (wid >> 1) * 32, wn = (wid & 1) * 64;
  const int l16 = lane & 15, quad = lane >> 4;
#pragma unroll
  for (int tm = 0; tm < 2; tm++)
#pragma unroll
    for (int tn = 0; tn < 4; tn++)
#pragma unroll
      for (int i = 0; i < 4; i++) {
        int r = wm + tm * 16 + quad * 4 + i;
        int c = wn + tn * 16 + l16;
        float v = acc.t[tm][tn][i] * scale;
        out[transposed ? (c * 128 + r) : (r * 128 + c)] = f2b(v);
      }
}

// generic block reduction; nw = waves in block. Returns total to ALL threads.
__device__ __forceinline__ float block_sum(float v, float* red, int nw) {
#pragma unroll
  for (int off = 32; off > 0; off >>= 1) v += __shfl_down(v, off);
  int wid = threadIdx.x >> 6;
  if ((threadIdx.x & 63) == 0) red[wid] = v;
  __syncthreads();
  if (threadIdx.x == 0) {
    float s = 0.f;
    for (int w = 0; w < nw; w++) s += red[w];
    red[0] = s;
  }
  __syncthreads();
  float s = red[0];
  __syncthreads();
  return s;
}

// ---------------- K1: round-1 basis products ----------------
__global__ __launch_bounds__(512) void k1(const float* __restrict__ cores,
                                          u16* __restrict__ T) {
  __shared__ u16 A0[128 * HP], A1[128 * HP], B0[128 * HP], B1[128 * HP];
  const int j = blockIdx.x;  // 0..126 -> pair (o_{2j+1}, o_{2j+2})
  const float* c1 = cores + (size_t)(2 * j + 1) * 32768;
  const float* c2 = cores + (size_t)(2 * j + 2) * 32768;
  const int tid = threadIdx.x;
#pragma unroll 4
  for (int i = 0; i < 32; i++) {
    int lh = tid + i * 512;  // 0..16383
    int l = lh >> 7, h = lh & 127;
    float a0 = c1[(l * 2 + 0) * 128 + h];
    float a1 = c1[(l * 2 + 1) * 128 + h];
    A0[l * HP + h] = f2b(a0);
    A1[l * HP + h] = f2b(a1 - a0);
    float b0 = c2[(l * 2 + 0) * 128 + h];
    float b1 = c2[(l * 2 + 1) * 128 + h];
    B0[h * HP + l] = f2b(b0);  // B basis transposed in LDS
    B1[h * HP + l] = f2b(b1 - b0);
  }
  __syncthreads();
  const bool tr = (j % 2) == 0;  // even -> consumed as B operand -> store C^T
  u16* Tj = T + (size_t)j * 4 * 16384;
  Acc8 acc;
  mfma128_w8(A0, B0, acc); store_tile8(Tj + 0 * 16384, acc, 1.f, tr);
  mfma128_w8(A0, B1, acc); store_tile8(Tj + 1 * 16384, acc, 1.f, tr);  // coeff b
  mfma128_w8(A1, B0, acc); store_tile8(Tj + 2 * 16384, acc, 1.f, tr);  // coeff a
  mfma128_w8(A1, B1, acc); store_tile8(Tj + 3 * 16384, acc, 1.f, tr);  // coeff ab
}

// ---------------- K1b: round-2 basis TT_t = T1_p @ T2_q ----------------
__global__ __launch_bounds__(512) void k1b(const u16* __restrict__ T,
                                           u16* __restrict__ TT) {
  __shared__ u16 Ald[128 * HP], Bld[128 * HP];
  const int t = blockIdx.x;   // 0..15 : p = t>>2, q = t&3
  const int j2 = blockIdx.y;  // 0..62
  const int m1 = 2 * j2 + 1, m2 = 2 * j2 + 2;
  const u16* TA = T + ((size_t)m1 * 4 + (t >> 2)) * 16384;  // odd -> row-major
  const u16* TB = T + ((size_t)m2 * 4 + (t & 3)) * 16384;   // even -> [n][k] flat
  const int tid = threadIdx.x;
#pragma unroll
  for (int i = 0; i < 4; i++) {
    int g8 = tid + i * 512;
    int r = g8 >> 4, c8 = g8 & 15;
    *(uint4*)(Ald + r * HP + c8 * 8) = *(const uint4*)(TA + g8 * 8);
    *(uint4*)(Bld + r * HP + c8 * 8) = *(const uint4*)(TB + g8 * 8);
  }
  __syncthreads();
  Acc8 acc;
  mfma128_w8(Ald, Bld, acc);
  store_tile8(TT + ((size_t)j2 * 16 + t) * 16384, acc, 1.f, (j2 % 2) == 0);
}

// ---------------- K1c: Gram G[j2] = V V^T (16x16, K=16384) ----------------
__global__ __launch_bounds__(256) void k1c(const u16* __restrict__ TT,
                                           float* __restrict__ G) {
  __shared__ float Gp[1024];
  const int j2 = blockIdx.x;
  const int tid = threadIdx.x;
  const int w = tid >> 6, lane = tid & 63;
  const int l16 = lane & 15, quad = lane >> 4;
  const u16* V = TT + (size_t)j2 * 16 * 16384 + (size_t)l16 * 16384;
  f32x4 acc = (f32x4){0.f, 0.f, 0.f, 0.f};
  for (int kk = w * 4096; kk < w * 4096 + 4096; kk += 32) {
    short8 av = *(const short8*)(V + kk + quad * 8);
    acc = __builtin_amdgcn_mfma_f32_16x16x32_bf16(av, av, acc, 0, 0, 0);
  }
#pragma unroll
  for (int i = 0; i < 4; i++)
    Gp[w * 256 + (quad * 4 + i) * 16 + l16] = acc[i];
  __syncthreads();
  G[(size_t)j2 * 256 + tid] = Gp[tid] + Gp[256 + tid] + Gp[512 + tid] + Gp[768 + tid];
}

// ---------------- K2n: coeffs, norms, logs ----------------
__global__ __launch_bounds__(64) void k2n(const float* __restrict__ x,
                                          const float* __restrict__ G,
                                          float* __restrict__ cbuf,
                                          float* __restrict__ invn,
                                          float* __restrict__ logs) {
  __shared__ float Gs[256];
  const int j2 = blockIdx.x;
  const int b = threadIdx.x;
#pragma unroll
  for (int i = 0; i < 4; i++) Gs[b + i * 64] = G[(size_t)j2 * 256 + b + i * 64];
  __syncthreads();
  const float* xb = x + b * 256;
  const int m1 = 2 * j2 + 1, m2 = 2 * j2 + 2;
  float a1 = xb[2 * m1 + 2], b1 = xb[2 * m1 + 3];
  float a2 = xb[2 * m2 + 2], b2 = xb[2 * m2 + 3];
  float c1[4] = {1.f, b1, a1, a1 * b1};
  float c2[4] = {1.f, b2, a2, a2 * b2};
  float c[16];
#pragma unroll
  for (int p = 0; p < 4; p++)
#pragma unroll
    for (int q = 0; q < 4; q++) c[p * 4 + q] = c1[p] * c2[q];
  float n2 = 0.f;
#pragma unroll
  for (int t = 0; t < 16; t++) {
    float s = 0.f;
#pragma unroll
    for (int u = 0; u < 16; u++) s += Gs[t * 16 + u] * c[u];
    n2 += c[t] * s;
  }
  float n = fmaxf(sqrtf(n2), 1e-12f);
  logs[b * 127 + 1 + j2] = logf(n);
  invn[j2 * 64 + b] = 1.f / n;
#pragma unroll
  for (int t = 0; t < 16; t++) cbuf[((size_t)j2 * 64 + b) * 16 + t] = c[t];
}

// ---------------- K2s: special chain, rounds 1+2 ----------------
__global__ __launch_bounds__(128) void k2s(const float* __restrict__ x,
                                           const float* __restrict__ core0,
                                           const float* __restrict__ cores,
                                           const u16* __restrict__ T,
                                           float* __restrict__ sA,
                                           float* __restrict__ logs) {
  __shared__ float svec[128];
  __shared__ float red[8];
  const int b = blockIdx.x, tid = threadIdx.x;
  const float* xb = x + b * 256;
  float x0 = xb[0], x1 = xb[1];
  float c00 = core0[tid], c01 = core0[128 + tid];
  svec[tid] = c00 * (1.f - x0) + c01 * x0;
  __syncthreads();
  float acc1 = 0.f;
  for (int k = 0; k < 128; k++) {
    float m0 = cores[(k * 2 + 0) * 128 + tid];
    float m1 = cores[(k * 2 + 1) * 128 + tid];
    acc1 += svec[k] * (m0 + x1 * (m1 - m0));
  }
  float tot = block_sum(acc1 * acc1, red, 2);
  float n1 = fmaxf(sqrtf(tot), 1e-12f);
  float ln = logf(n1);
  svec[tid] = acc1 / n1;
  __syncthreads();
  // combo with T[0] basis (transposed flat [h*128+k]); telescoped log.
  float a = xb[2], bb = xb[3], ab = a * bb;
  float acc2 = 0.f;
  for (int k8 = 0; k8 < 16; k8++) {
    union { uint4 v; u16 s[8]; } q00, q01, q10, q11;
    q00.v = *(const uint4*)(T + tid * 128 + k8 * 8);
    q01.v = *(const uint4*)(T + 16384 + tid * 128 + k8 * 8);
    q10.v = *(const uint4*)(T + 32768 + tid * 128 + k8 * 8);
    q11.v = *(const uint4*)(T + 49152 + tid * 128 + k8 * 8);
#pragma unroll
    for (int e = 0; e < 8; e++) {
      float pk = b2f(q00.s[e]) + a * b2f(q10.s[e]) + bb * b2f(q01.s[e]) +
                 ab * b2f(q11.s[e]);
      acc2 += svec[k8 * 8 + e] * pk;
    }
  }
  float tot2 = block_sum(acc2 * acc2, red, 2);
  float n2 = fmaxf(sqrtf(tot2), 1e-12f);
  sA[b * 128 + tid] = acc2 / n2;
  if (tid == 0) logs[b * 127 + 0] = ln + logf(n2);
}

// ---------------- K2c: element-wise combine, register-resident ----------------
__global__ __launch_bounds__(256) void k2c(const u16* __restrict__ TT,
                                           const float* __restrict__ cbuf,
                                           const float* __restrict__ invn,
                                           u16* __restrict__ M0) {
  const int slice = blockIdx.x;  // 0..15, 1024 elems each
  const int j2 = blockIdx.y;
  const int tid = threadIdx.x;
  const int e0 = slice * 1024 + tid * 4;
  float v[16][4];
#pragma unroll
  for (int t = 0; t < 16; t++) {
    union { uint2 u; u16 s[4]; } q;
    q.u = *(const uint2*)(TT + ((size_t)j2 * 16 + t) * 16384 + e0);
#pragma unroll
    for (int i = 0; i < 4; i++) v[t][i] = b2f(q.s[i]);
  }
  const float* cb0 = cbuf + (size_t)j2 * 64 * 16;
  const float* in0 = invn + (size_t)j2 * 64;
  u16* out = M0 + (size_t)j2 * 16384 + e0;
  for (int b = 0; b < 64; b++) {
    const float* cb = cb0 + b * 16;
    float inv = in0[b];
    float o[4] = {0.f, 0.f, 0.f, 0.f};
#pragma unroll
    for (int t = 0; t < 16; t++) {
      float ct = cb[t];
#pragma unroll
      for (int i = 0; i < 4; i++) o[i] += ct * v[t][i];
    }
    union { uint2 u; u16 s[4]; } r;
#pragma unroll
    for (int i = 0; i < 4; i++) r.s[i] = f2b(o[i] * inv);
    *(uint2*)(out + (size_t)b * 63 * 16384) = r.u;
  }
}

// ---------------- R3,R4: pairwise round (512 threads) ----------------
__global__ __launch_bounds__(512) void roundk(const u16* __restrict__ In,
                                              u16* __restrict__ Out,
                                              const float* __restrict__ sIn,
                                              float* __restrict__ sOut,
                                              float* __restrict__ logs,
                                              int count_in, int slot0) {
  __shared__ u16 Ald[128 * HP], Bld[128 * HP];
  __shared__ float red[8];
  const int b = blockIdx.y, p = blockIdx.x, tid = threadIdx.x;

  if (p == 0) {
    float* svec = (float*)Ald;
    if (tid < 128) svec[tid] = sIn[b * 128 + tid];
    __syncthreads();
    const u16* M = In + (size_t)b * count_in * 16384;  // In[b][0], transposed
    float acc = 0.f;
    if (tid < 128) {
      for (int k8 = 0; k8 < 16; k8++) {
        union { uint4 v; u16 s[8]; } q;
        q.v = *(const uint4*)(M + tid * 128 + k8 * 8);
#pragma unroll
        for (int e = 0; e < 8; e++) acc += svec[k8 * 8 + e] * b2f(q.s[e]);
      }
    }
    float tot = block_sum((tid < 128) ? acc * acc : 0.f, red, 8);
    float n = fmaxf(sqrtf(tot), 1e-12f);
    if (tid < 128) sOut[b * 128 + tid] = acc / n;
    if (tid == 0) logs[b * 127 + slot0] = logf(n);
  } else {
    const u16* A = In + ((size_t)b * count_in + (2 * p - 1)) * 16384;
    const u16* Bm = In + ((size_t)b * count_in + (2 * p)) * 16384;
#pragma unroll
    for (int i = 0; i < 4; i++) {
      int g8 = tid + i * 512;
      int r = g8 >> 4, c8 = g8 & 15;
      *(uint4*)(Ald + r * HP + c8 * 8) = *(const uint4*)(A + g8 * 8);
      *(uint4*)(Bld + r * HP + c8 * 8) = *(const uint4*)(Bm + g8 * 8);
    }
    __syncthreads();
    Acc8 acc;
    mfma128_w8(Ald, Bld, acc);
    float tot = block_sum(acc_sumsq8(acc), red, 8);
    float n = fmaxf(sqrtf(tot), 1e-12f);
    if (tid == 0) logs[b * 127 + slot0 + p] = logf(n);
    int m = p - 1;
    int count_out = (count_in - 1) / 2;
    store_tile8(Out + ((size_t)b * count_out + m) * 16384, acc, 1.f / n,
                (m % 2) == 0);
  }
}

// ---------------- tail: R5..R8 + logits, one block per batch ----------------
__global__ __launch_bounds__(512) void tailk(const u16* __restrict__ In15,
                                             u16* __restrict__ scr,
                                             const float* __restrict__ sIn,
                                             const float* __restrict__ logs,
                                             const float* __restrict__ cls,
                                             float* __restrict__ out) {
  __shared__ u16 Ald[128 * HP], Bld[128 * HP];
  __shared__ float svec[128];
  __shared__ float red[8];
  const int b = blockIdx.x, tid = threadIdx.x;
  if (tid < 128) svec[tid] = sIn[b * 128 + tid];
  __syncthreads();
  float lg = 0.f;

  const int cins[3] = {15, 7, 3};
  const u16* curIn = In15 + (size_t)b * 15 * 16384;
  u16* outs[3] = {scr + (size_t)b * 7 * 16384,
                  scr + ((size_t)64 * 7 + (size_t)b * 3) * 16384,
                  scr + ((size_t)64 * 10 + (size_t)b) * 16384};

  for (int r = 0; r < 4; r++) {
    int cin = (r < 3) ? cins[r] : 1;
    int np = cin >> 1;
    for (int p = 1; p <= np; p++) {
      const u16* A = curIn + (size_t)(2 * p - 1) * 16384;
      const u16* Bm = curIn + (size_t)(2 * p) * 16384;
#pragma unroll
      for (int i = 0; i < 4; i++) {
        int g8 = tid + i * 512;
        int rr = g8 >> 4, c8 = g8 & 15;
        *(uint4*)(Ald + rr * HP + c8 * 8) = *(const uint4*)(A + g8 * 8);
        *(uint4*)(Bld + rr * HP + c8 * 8) = *(const uint4*)(Bm + g8 * 8);
      }
      __syncthreads();
      Acc8 acc;
      mfma128_w8(Ald, Bld, acc);
      float tot = block_sum(acc_sumsq8(acc), red, 8);
      float n = fmaxf(sqrtf(tot), 1e-12f);
      lg += logf(n);
      store_tile8(outs[r] + (size_t)(p - 1) * 16384, acc, 1.f / n,
                  ((p - 1) % 2) == 0);
      __syncthreads();
    }
    // special: svec . curIn[0] (transposed layout)
    float acc = 0.f;
    if (tid < 128) {
      for (int k8 = 0; k8 < 16; k8++) {
        union { uint4 v; u16 s[8]; } q;
        q.v = *(const uint4*)(curIn + tid * 128 + k8 * 8);
#pragma unroll
        for (int e = 0; e < 8; e++) acc += svec[k8 * 8 + e] * b2f(q.s[e]);
      }
    }
    float tot = block_sum((tid < 128) ? acc * acc : 0.f, red, 8);
    float n = fmaxf(sqrtf(tot), 1e-12f);
    lg += logf(n);
    if (tid < 128) svec[tid] = acc / n;
    __syncthreads();
    if (r < 3) curIn = outs[r];
  }
  // logits
  if (tid < 10) {
    float a = 0.f;
    for (int h = 0; h < 128; h++) a += svec[h] * cls[tid * 128 + h];
    float L = lg;
    for (int i = 0; i < 112; i++) L += logs[b * 127 + i];
    out[b * 10 + tid] = a + L;
  }
}

extern "C" void kernel_launch(void* const* d_in, const int* in_sizes, int n_in,
                              void* d_out, int out_size, void* d_ws, size_t ws_size,
                              hipStream_t stream) {
  (void)in_sizes; (void)n_in; (void)out_size; (void)ws_size;
  const float* x     = (const float*)d_in[0];  // (64,256)
  const float* core0 = (const float*)d_in[1];  // (1,2,128)
  const float* cores = (const float*)d_in[2];  // (255,128,2,128)
  const float* cls   = (const float*)d_in[3];  // (10,128)
  float* out = (float*)d_out;
  char* ws = (char*)d_ws;

  // Region A (65 MB): early = T (16.6 MB) + TT (33 MB); later reused as M1.
  constexpr size_t SZ_T  = (size_t)127 * 4 * 16384 * 2;   //  16,646,144
  constexpr size_t SZ_TT = (size_t)63 * 16 * 16384 * 2;   //  33,030,144
  constexpr size_t SZ_A  = (size_t)64 * 31 * 16384 * 2;   //  65,011,712 (M1)
  constexpr size_t SZ_M0 = (size_t)64 * 63 * 16384 * 2;   // 132,120,576

  u16*   T    = (u16*)(ws);
  u16*   TT   = (u16*)(ws + SZ_T);
  u16*   M1   = (u16*)(ws);            // aliases T+TT after K2c completes
  u16*   M0   = (u16*)(ws + SZ_A);
  char*  tail0 = ws + SZ_A + SZ_M0;
  float* G    = (float*)(tail0);                       // 63*256*4 = 64,512
  float* cbuf = (float*)(tail0 + 65536);               // 63*64*16*4 = 258,048
  float* invn = (float*)(tail0 + 65536 + 262144);      // 16,128
  float* sA   = (float*)(tail0 + 65536 + 262144 + 16384);
  float* sB   = (float*)(tail0 + 65536 + 262144 + 16384 + 32768);
  float* logs = (float*)(tail0 + 65536 + 262144 + 16384 + 65536);

  k1 <<<dim3(127), 512, 0, stream>>>(cores, T);
  k1b<<<dim3(16, 63), 512, 0, stream>>>(T, TT);
  k1c<<<dim3(63), 256, 0, stream>>>(TT, G);
  k2n<<<dim3(63), 64, 0, stream>>>(x, G, cbuf, invn, logs);
  k2s<<<dim3(64), 128, 0, stream>>>(x, core0, cores, T, sA, logs);
  k2c<<<dim3(16, 63), 256, 0, stream>>>(TT, cbuf, invn, M0);
  // log slots: 0 special(r1+r2), 1..63 pairs(r1+r2), R3 64..95, R4 96..111,
  //            tail accumulates 112..126 internally.
  roundk<<<dim3(32, 64), 512, 0, stream>>>(M0, M1, sA, sB, logs, 63, 64);
  roundk<<<dim3(16, 64), 512, 0, stream>>>(M1, M0, sB, sA, logs, 31, 96);
  tailk <<<dim3(64), 512, 0, stream>>>(M0, M1, sA, logs, cls, out);
}

// Round 4
// 409.891 us; speedup vs baseline: 1.1064x; 1.1064x over previous
//
#include <hip/hip_runtime.h>
#include <stdint.h>

// MPS classifier forward, MI355X.
//   K1 : 127 blocks, round-1 basis T_pq = {C0,dC}_n1 @ {C0,dC}_n2 (bf16, parity layout)
//   K1b: 63x16 blocks, round-2 basis TT_t = T1_p @ T2_q  (batch-independent!)
//   K1c: Gram G[j2] = V V^T (16x16) over TT basis via MFMA
//   K2n: per (j2,b): coeffs c[16], n = sqrt(c^T G c), log n (telescoped r1+r2 logs)
//   K2s: special chain rounds 1+2 (64 blocks)
//   K2c: element-wise combine M0 = (sum_t c_t TT_t)/n, register-resident TT slice,
//        batch-split over blockIdx.z
//   R3..R7: pairwise rounds, 512-thread blocks (8 waves), per-node normalization
//   final8: R8 (special dot) + logits, 64 blocks

typedef unsigned short u16;
typedef __attribute__((ext_vector_type(8))) short short8;
typedef __attribute__((ext_vector_type(4))) float f32x4;

#define HP 136  // LDS row stride in bf16: 272 B, 16B-aligned, 2-way-bank-free

__device__ __forceinline__ u16 f2b(float f) {
  uint32_t u = __builtin_bit_cast(uint32_t, f);
  u += 0x7FFFu + ((u >> 16) & 1u);
  return (u16)(u >> 16);
}
__device__ __forceinline__ float b2f(u16 b) {
  uint32_t u = ((uint32_t)b) << 16;
  return __builtin_bit_cast(float, u);
}

struct Acc8 { f32x4 t[2][4]; };

// 512-thread (8-wave) 128x128x128: wave tile 32x64. A: [m][k] LDS, B: [n][k] LDS.
__device__ __forceinline__ void mfma128_w8(const u16* Alds, const u16* Blds,
                                           Acc8& acc) {
  const int tid = threadIdx.x;
  const int wid = tid >> 6, lane = tid & 63;
  const int wm = (wid >> 1) * 32, wn = (wid & 1) * 64;
  const int l16 = lane & 15, quad = lane >> 4;
#pragma unroll
  for (int tm = 0; tm < 2; tm++)
#pragma unroll
    for (int tn = 0; tn < 4; tn++)
      acc.t[tm][tn] = (f32x4){0.f, 0.f, 0.f, 0.f};
#pragma unroll
  for (int kk = 0; kk < 128; kk += 32) {
    short8 af[2], bf[4];
#pragma unroll
    for (int t = 0; t < 2; t++)
      af[t] = *(const short8*)(Alds + (wm + t * 16 + l16) * HP + kk + quad * 8);
#pragma unroll
    for (int t = 0; t < 4; t++)
      bf[t] = *(const short8*)(Blds + (wn + t * 16 + l16) * HP + kk + quad * 8);
#pragma unroll
    for (int tm = 0; tm < 2; tm++)
#pragma unroll
      for (int tn = 0; tn < 4; tn++)
        acc.t[tm][tn] = __builtin_amdgcn_mfma_f32_16x16x32_bf16(
            af[tm], bf[tn], acc.t[tm][tn], 0, 0, 0);
  }
}

__device__ __forceinline__ float acc_sumsq8(const Acc8& acc) {
  float ss = 0.f;
#pragma unroll
  for (int tm = 0; tm < 2; tm++)
#pragma unroll
    for (int tn = 0; tn < 4; tn++)
#pragma unroll
      for (int i = 0; i < 4; i++) {
        float v = acc.t[tm][tn][i];
        ss += v * v;
      }
  return ss;
}

// C/D layout (m89): row = quad*4 + reg, col = lane&15 per 16x16 tile.
__device__ __forceinline__ void store_tile8(u16* out, const Acc8& acc, float scale,
                                            bool transposed) {
  const int tid = threadIdx.x;
  const int wid = tid >> 6, lane = tid & 63;
  const int wm = (wid >> 1) * 32, wn = (wid & 1) * 64;
  const int l16 = lane & 15, quad = lane >> 4;
#pragma unroll
  for (int tm = 0; tm < 2; tm++)
#pragma unroll
    for (int tn = 0; tn < 4; tn++)
#pragma unroll
      for (int i = 0; i < 4; i++) {
        int r = wm + tm * 16 + quad * 4 + i;
        int c = wn + tn * 16 + l16;
        float v = acc.t[tm][tn][i] * scale;
        out[transposed ? (c * 128 + r) : (r * 128 + c)] = f2b(v);
      }
}

__device__ __forceinline__ float block_sum(float v, float* red, int nw) {
#pragma unroll
  for (int off = 32; off > 0; off >>= 1) v += __shfl_down(v, off);
  int wid = threadIdx.x >> 6;
  if ((threadIdx.x & 63) == 0) red[wid] = v;
  __syncthreads();
  if (threadIdx.x == 0) {
    float s = 0.f;
    for (int w = 0; w < nw; w++) s += red[w];
    red[0] = s;
  }
  __syncthreads();
  float s = red[0];
  __syncthreads();
  return s;
}

// ---------------- K1: round-1 basis products ----------------
__global__ __launch_bounds__(512) void k1(const float* __restrict__ cores,
                                          u16* __restrict__ T) {
  __shared__ u16 A0[128 * HP], A1[128 * HP], B0[128 * HP], B1[128 * HP];
  const int j = blockIdx.x;  // 0..126 -> pair (o_{2j+1}, o_{2j+2})
  const float* c1 = cores + (size_t)(2 * j + 1) * 32768;
  const float* c2 = cores + (size_t)(2 * j + 2) * 32768;
  const int tid = threadIdx.x;
#pragma unroll 4
  for (int i = 0; i < 32; i++) {
    int lh = tid + i * 512;
    int l = lh >> 7, h = lh & 127;
    float a0 = c1[(l * 2 + 0) * 128 + h];
    float a1 = c1[(l * 2 + 1) * 128 + h];
    A0[l * HP + h] = f2b(a0);
    A1[l * HP + h] = f2b(a1 - a0);
    float b0 = c2[(l * 2 + 0) * 128 + h];
    float b1 = c2[(l * 2 + 1) * 128 + h];
    B0[h * HP + l] = f2b(b0);  // B basis transposed in LDS
    B1[h * HP + l] = f2b(b1 - b0);
  }
  __syncthreads();
  const bool tr = (j % 2) == 0;  // even -> consumed as B operand -> store C^T
  u16* Tj = T + (size_t)j * 4 * 16384;
  Acc8 acc;
  mfma128_w8(A0, B0, acc); store_tile8(Tj + 0 * 16384, acc, 1.f, tr);
  mfma128_w8(A0, B1, acc); store_tile8(Tj + 1 * 16384, acc, 1.f, tr);  // coeff b
  mfma128_w8(A1, B0, acc); store_tile8(Tj + 2 * 16384, acc, 1.f, tr);  // coeff a
  mfma128_w8(A1, B1, acc); store_tile8(Tj + 3 * 16384, acc, 1.f, tr);  // coeff ab
}

// ---------------- K1b: round-2 basis TT_t = T1_p @ T2_q ----------------
__global__ __launch_bounds__(512) void k1b(const u16* __restrict__ T,
                                           u16* __restrict__ TT) {
  __shared__ u16 Ald[128 * HP], Bld[128 * HP];
  const int t = blockIdx.x;   // 0..15 : p = t>>2, q = t&3
  const int j2 = blockIdx.y;  // 0..62
  const int m1 = 2 * j2 + 1, m2 = 2 * j2 + 2;
  const u16* TA = T + ((size_t)m1 * 4 + (t >> 2)) * 16384;  // odd -> row-major
  const u16* TB = T + ((size_t)m2 * 4 + (t & 3)) * 16384;   // even -> [n][k] flat
  const int tid = threadIdx.x;
#pragma unroll
  for (int i = 0; i < 4; i++) {
    int g8 = tid + i * 512;
    int r = g8 >> 4, c8 = g8 & 15;
    *(uint4*)(Ald + r * HP + c8 * 8) = *(const uint4*)(TA + g8 * 8);
    *(uint4*)(Bld + r * HP + c8 * 8) = *(const uint4*)(TB + g8 * 8);
  }
  __syncthreads();
  Acc8 acc;
  mfma128_w8(Ald, Bld, acc);
  store_tile8(TT + ((size_t)j2 * 16 + t) * 16384, acc, 1.f, (j2 % 2) == 0);
}

// ---------------- K1c: Gram G[j2] = V V^T (16x16, K=16384) ----------------
__global__ __launch_bounds__(256) void k1c(const u16* __restrict__ TT,
                                           float* __restrict__ G) {
  __shared__ float Gp[1024];
  const int j2 = blockIdx.x;
  const int tid = threadIdx.x;
  const int w = tid >> 6, lane = tid & 63;
  const int l16 = lane & 15, quad = lane >> 4;
  const u16* V = TT + (size_t)j2 * 16 * 16384 + (size_t)l16 * 16384;
  f32x4 acc = (f32x4){0.f, 0.f, 0.f, 0.f};
  for (int kk = w * 4096; kk < w * 4096 + 4096; kk += 32) {
    short8 av = *(const short8*)(V + kk + quad * 8);
    acc = __builtin_amdgcn_mfma_f32_16x16x32_bf16(av, av, acc, 0, 0, 0);
  }
#pragma unroll
  for (int i = 0; i < 4; i++)
    Gp[w * 256 + (quad * 4 + i) * 16 + l16] = acc[i];
  __syncthreads();
  G[(size_t)j2 * 256 + tid] = Gp[tid] + Gp[256 + tid] + Gp[512 + tid] + Gp[768 + tid];
}

// ---------------- K2n: coeffs, norms, logs ----------------
__global__ __launch_bounds__(64) void k2n(const float* __restrict__ x,
                                          const float* __restrict__ G,
                                          float* __restrict__ cbuf,
                                          float* __restrict__ invn,
                                          float* __restrict__ logs) {
  __shared__ float Gs[256];
  const int j2 = blockIdx.x;
  const int b = threadIdx.x;
#pragma unroll
  for (int i = 0; i < 4; i++) Gs[b + i * 64] = G[(size_t)j2 * 256 + b + i * 64];
  __syncthreads();
  const float* xb = x + b * 256;
  const int m1 = 2 * j2 + 1, m2 = 2 * j2 + 2;
  float a1 = xb[2 * m1 + 2], b1 = xb[2 * m1 + 3];
  float a2 = xb[2 * m2 + 2], b2 = xb[2 * m2 + 3];
  float c1[4] = {1.f, b1, a1, a1 * b1};
  float c2[4] = {1.f, b2, a2, a2 * b2};
  float c[16];
#pragma unroll
  for (int p = 0; p < 4; p++)
#pragma unroll
    for (int q = 0; q < 4; q++) c[p * 4 + q] = c1[p] * c2[q];
  float n2 = 0.f;
#pragma unroll
  for (int t = 0; t < 16; t++) {
    float s = 0.f;
#pragma unroll
    for (int u = 0; u < 16; u++) s += Gs[t * 16 + u] * c[u];
    n2 += c[t] * s;
  }
  float n = fmaxf(sqrtf(n2), 1e-12f);
  logs[b * 127 + 1 + j2] = logf(n);
  invn[j2 * 64 + b] = 1.f / n;
#pragma unroll
  for (int t = 0; t < 16; t++) cbuf[((size_t)j2 * 64 + b) * 16 + t] = c[t];
}

// ---------------- K2s: special chain, rounds 1+2 ----------------
__global__ __launch_bounds__(128) void k2s(const float* __restrict__ x,
                                           const float* __restrict__ core0,
                                           const float* __restrict__ cores,
                                           const u16* __restrict__ T,
                                           float* __restrict__ sA,
                                           float* __restrict__ logs) {
  __shared__ float svec[128];
  __shared__ float red[8];
  const int b = blockIdx.x, tid = threadIdx.x;
  const float* xb = x + b * 256;
  float x0 = xb[0], x1 = xb[1];
  svec[tid] = core0[tid] * (1.f - x0) + core0[128 + tid] * x0;
  __syncthreads();
  float acc1 = 0.f;
  for (int k = 0; k < 128; k++) {
    float m0 = cores[(k * 2 + 0) * 128 + tid];
    float m1 = cores[(k * 2 + 1) * 128 + tid];
    acc1 += svec[k] * (m0 + x1 * (m1 - m0));
  }
  float tot = block_sum(acc1 * acc1, red, 2);
  float n1 = fmaxf(sqrtf(tot), 1e-12f);
  float ln = logf(n1);
  svec[tid] = acc1 / n1;
  __syncthreads();
  // combo with T[0] basis (transposed flat [h*128+k]); telescoped log.
  float a = xb[2], bb = xb[3], ab = a * bb;
  float acc2 = 0.f;
  for (int k8 = 0; k8 < 16; k8++) {
    union { uint4 v; u16 s[8]; } q00, q01, q10, q11;
    q00.v = *(const uint4*)(T + tid * 128 + k8 * 8);
    q01.v = *(const uint4*)(T + 16384 + tid * 128 + k8 * 8);
    q10.v = *(const uint4*)(T + 32768 + tid * 128 + k8 * 8);
    q11.v = *(const uint4*)(T + 49152 + tid * 128 + k8 * 8);
#pragma unroll
    for (int e = 0; e < 8; e++) {
      float pk = b2f(q00.s[e]) + a * b2f(q10.s[e]) + bb * b2f(q01.s[e]) +
                 ab * b2f(q11.s[e]);
      acc2 += svec[k8 * 8 + e] * pk;
    }
  }
  float tot2 = block_sum(acc2 * acc2, red, 2);
  float n2 = fmaxf(sqrtf(tot2), 1e-12f);
  sA[b * 128 + tid] = acc2 / n2;
  if (tid == 0) logs[b * 127 + 0] = ln + logf(n2);
}

// ---------------- K2c: element-wise combine, batch-split ----------------
__global__ __launch_bounds__(256) void k2c(const u16* __restrict__ TT,
                                           const float* __restrict__ cbuf,
                                           const float* __restrict__ invn,
                                           u16* __restrict__ M0) {
  const int slice = blockIdx.x;  // 0..15, 1024 elems each
  const int j2 = blockIdx.y;
  const int bz = blockIdx.z;     // 0..3, 16 batches each
  const int tid = threadIdx.x;
  const int e0 = slice * 1024 + tid * 4;
  float v[16][4];
#pragma unroll
  for (int t = 0; t < 16; t++) {
    union { uint2 u; u16 s[4]; } q;
    q.u = *(const uint2*)(TT + ((size_t)j2 * 16 + t) * 16384 + e0);
#pragma unroll
    for (int i = 0; i < 4; i++) v[t][i] = b2f(q.s[i]);
  }
  const float* cb0 = cbuf + (size_t)j2 * 64 * 16;
  const float* in0 = invn + (size_t)j2 * 64;
  u16* out = M0 + (size_t)j2 * 16384 + e0;
  for (int b = bz * 16; b < bz * 16 + 16; b++) {
    const float* cb = cb0 + b * 16;
    float inv = in0[b];
    float o[4] = {0.f, 0.f, 0.f, 0.f};
#pragma unroll
    for (int t = 0; t < 16; t++) {
      float ct = cb[t];
#pragma unroll
      for (int i = 0; i < 4; i++) o[i] += ct * v[t][i];
    }
    union { uint2 u; u16 s[4]; } r;
#pragma unroll
    for (int i = 0; i < 4; i++) r.s[i] = f2b(o[i] * inv);
    *(uint2*)(out + (size_t)b * 63 * 16384) = r.u;
  }
}

// ---------------- R3..R7: pairwise round (512 threads) ----------------
__global__ __launch_bounds__(512) void roundk(const u16* __restrict__ In,
                                              u16* __restrict__ Out,
                                              const float* __restrict__ sIn,
                                              float* __restrict__ sOut,
                                              float* __restrict__ logs,
                                              int count_in, int slot0) {
  __shared__ u16 Ald[128 * HP], Bld[128 * HP];
  __shared__ float red[8];
  const int b = blockIdx.y, p = blockIdx.x, tid = threadIdx.x;

  if (p == 0) {
    float* svec = (float*)Ald;
    if (tid < 128) svec[tid] = sIn[b * 128 + tid];
    __syncthreads();
    const u16* M = In + (size_t)b * count_in * 16384;  // In[b][0], transposed
    float acc = 0.f;
    if (tid < 128) {
      for (int k8 = 0; k8 < 16; k8++) {
        union { uint4 v; u16 s[8]; } q;
        q.v = *(const uint4*)(M + tid * 128 + k8 * 8);
#pragma unroll
        for (int e = 0; e < 8; e++) acc += svec[k8 * 8 + e] * b2f(q.s[e]);
      }
    }
    float tot = block_sum((tid < 128) ? acc * acc : 0.f, red, 8);
    float n = fmaxf(sqrtf(tot), 1e-12f);
    if (tid < 128) sOut[b * 128 + tid] = acc / n;
    if (tid == 0) logs[b * 127 + slot0] = logf(n);
  } else {
    const u16* A = In + ((size_t)b * count_in + (2 * p - 1)) * 16384;
    const u16* Bm = In + ((size_t)b * count_in + (2 * p)) * 16384;
#pragma unroll
    for (int i = 0; i < 4; i++) {
      int g8 = tid + i * 512;
      int r = g8 >> 4, c8 = g8 & 15;
      *(uint4*)(Ald + r * HP + c8 * 8) = *(const uint4*)(A + g8 * 8);
      *(uint4*)(Bld + r * HP + c8 * 8) = *(const uint4*)(Bm + g8 * 8);
    }
    __syncthreads();
    Acc8 acc;
    mfma128_w8(Ald, Bld, acc);
    float tot = block_sum(acc_sumsq8(acc), red, 8);
    float n = fmaxf(sqrtf(tot), 1e-12f);
    if (tid == 0) logs[b * 127 + slot0 + p] = logf(n);
    int m = p - 1;
    int count_out = (count_in - 1) / 2;
    store_tile8(Out + ((size_t)b * count_out + m) * 16384, acc, 1.f / n,
                (m % 2) == 0);
  }
}

// ---------------- final8: R8 special dot + logits ----------------
__global__ __launch_bounds__(128) void final8(const u16* __restrict__ In,
                                              const float* __restrict__ sIn,
                                              const float* __restrict__ logs,
                                              const float* __restrict__ cls,
                                              float* __restrict__ out) {
  __shared__ float svec[128], ovec[128], red[2];
  const int b = blockIdx.x, tid = threadIdx.x;
  svec[tid] = sIn[b * 128 + tid];
  __syncthreads();
  const u16* M = In + (size_t)b * 16384;  // count_in=1, transposed layout
  float acc = 0.f;
  for (int k8 = 0; k8 < 16; k8++) {
    union { uint4 v; u16 s[8]; } q;
    q.v = *(const uint4*)(M + tid * 128 + k8 * 8);
#pragma unroll
    for (int e = 0; e < 8; e++) acc += svec[k8 * 8 + e] * b2f(q.s[e]);
  }
  float tot = block_sum(acc * acc, red, 2);
  float n = fmaxf(sqrtf(tot), 1e-12f);
  ovec[tid] = acc / n;
  __syncthreads();
  if (tid < 10) {
    float a = 0.f;
    for (int h = 0; h < 128; h++) a += ovec[h] * cls[tid * 128 + h];
    float L = logf(n);
    for (int i = 0; i < 126; i++) L += logs[b * 127 + i];
    out[b * 10 + tid] = a + L;
  }
}

extern "C" void kernel_launch(void* const* d_in, const int* in_sizes, int n_in,
                              void* d_out, int out_size, void* d_ws, size_t ws_size,
                              hipStream_t stream) {
  (void)in_sizes; (void)n_in; (void)out_size; (void)ws_size;
  const float* x     = (const float*)d_in[0];  // (64,256)
  const float* core0 = (const float*)d_in[1];  // (1,2,128)
  const float* cores = (const float*)d_in[2];  // (255,128,2,128)
  const float* cls   = (const float*)d_in[3];  // (10,128)
  float* out = (float*)d_out;
  char* ws = (char*)d_ws;

  // Region A (65 MB): early = T (16.6 MB) + TT (33 MB); later reused as M1.
  constexpr size_t SZ_T  = (size_t)127 * 4 * 16384 * 2;   //  16,646,144
  constexpr size_t SZ_A  = (size_t)64 * 31 * 16384 * 2;   //  65,011,712 (M1)
  constexpr size_t SZ_M0 = (size_t)64 * 63 * 16384 * 2;   // 132,120,576

  u16*   T    = (u16*)(ws);
  u16*   TT   = (u16*)(ws + SZ_T);
  u16*   M1   = (u16*)(ws);            // aliases T+TT after K2c completes
  u16*   M0   = (u16*)(ws + SZ_A);
  char*  tail0 = ws + SZ_A + SZ_M0;
  float* G    = (float*)(tail0);                       // 63*256*4 = 64,512
  float* cbuf = (float*)(tail0 + 65536);               // 63*64*16*4 = 258,048
  float* invn = (float*)(tail0 + 65536 + 262144);      // 16,128
  float* sA   = (float*)(tail0 + 65536 + 262144 + 16384);
  float* sB   = (float*)(tail0 + 65536 + 262144 + 16384 + 32768);
  float* logs = (float*)(tail0 + 65536 + 262144 + 16384 + 65536);

  k1 <<<dim3(127), 512, 0, stream>>>(cores, T);
  k1b<<<dim3(16, 63), 512, 0, stream>>>(T, TT);
  k1c<<<dim3(63), 256, 0, stream>>>(TT, G);
  k2n<<<dim3(63), 64, 0, stream>>>(x, G, cbuf, invn, logs);
  k2s<<<dim3(64), 128, 0, stream>>>(x, core0, cores, T, sA, logs);
  k2c<<<dim3(16, 63, 4), 256, 0, stream>>>(TT, cbuf, invn, M0);
  // log slots: 0 special(r1+r2), 1..63 pairs(r1+r2), R3 64..95, R4 96..111,
  //            R5 112..119, R6 120..123, R7 124..125, final computes slot 126.
  roundk<<<dim3(32, 64), 512, 0, stream>>>(M0, M1, sA, sB, logs, 63, 64);
  roundk<<<dim3(16, 64), 512, 0, stream>>>(M1, M0, sB, sA, logs, 31, 96);
  roundk<<<dim3(8, 64),  512, 0, stream>>>(M0, M1, sA, sB, logs, 15, 112);
  roundk<<<dim3(4, 64),  512, 0, stream>>>(M1, M0, sB, sA, logs, 7, 120);
  roundk<<<dim3(2, 64),  512, 0, stream>>>(M0, M1, sB, sA, logs, 3, 124);
  final8<<<dim3(64), 128, 0, stream>>>(M1, sA, logs, cls, out);
}

// Round 5
// 280.579 us; speedup vs baseline: 1.6163x; 1.4609x over previous
//
#include <hip/hip_runtime.h>
#include <stdint.h>

// MPS classifier forward, MI355X.  (round-2 math preserved exactly; this round:
// 1024-thr matmul blocks (32 waves/CU), LDS-bounce coalesced stores, fewer launches)
//   k1  : (127,4) blocks, one round-1 basis product T[j][pq] per block
//   k1b : (16,63) blocks, round-2 basis TT_t = T1_p @ T2_q  (batch-independent)
//   k1c : (63,4) blocks, Gram partials over K-chunks
//   k2ns: 127 blocks: x<63 -> coeffs/norms/logs (k2n, sums Gram partials);
//         x>=63 -> special chain rounds 1+2 (k2s)
//   k2c : (16,63,8) element-wise combine M0 = (sum_t c_t TT_t)/n
//   R3..R6: pairwise rounds (roundk, 1024 thr)
//   r7f : R7 + R8 + logits fused, 64 blocks

typedef unsigned short u16;
typedef __attribute__((ext_vector_type(8))) short short8;
typedef __attribute__((ext_vector_type(4))) float f32x4;

#define HP 136  // LDS row stride in bf16: 272 B, 16B-aligned, 2-way-bank-free

__device__ __forceinline__ u16 f2b(float f) {
  uint32_t u = __builtin_bit_cast(uint32_t, f);
  u += 0x7FFFu + ((u >> 16) & 1u);
  return (u16)(u >> 16);
}
__device__ __forceinline__ float b2f(u16 b) {
  uint32_t u = ((uint32_t)b) << 16;
  return __builtin_bit_cast(float, u);
}

struct AccW { f32x4 t[2][2]; };  // 16-wave config: 32x32 wave tile

// 1024-thread (16-wave) 128x128x128. A: [m][k] LDS, B: [n][k] LDS.
__device__ __forceinline__ void mfma_w16(const u16* Alds, const u16* Blds,
                                         AccW& acc) {
  const int tid = threadIdx.x;
  const int wid = tid >> 6, lane = tid & 63;
  const int wm = (wid >> 2) * 32, wn = (wid & 3) * 32;
  const int l16 = lane & 15, quad = lane >> 4;
#pragma unroll
  for (int tm = 0; tm < 2; tm++)
#pragma unroll
    for (int tn = 0; tn < 2; tn++)
      acc.t[tm][tn] = (f32x4){0.f, 0.f, 0.f, 0.f};
#pragma unroll
  for (int kk = 0; kk < 128; kk += 32) {
    short8 af[2], bf[2];
#pragma unroll
    for (int t = 0; t < 2; t++) {
      af[t] = *(const short8*)(Alds + (wm + t * 16 + l16) * HP + kk + quad * 8);
      bf[t] = *(const short8*)(Blds + (wn + t * 16 + l16) * HP + kk + quad * 8);
    }
#pragma unroll
    for (int tm = 0; tm < 2; tm++)
#pragma unroll
      for (int tn = 0; tn < 2; tn++)
        acc.t[tm][tn] = __builtin_amdgcn_mfma_f32_16x16x32_bf16(
            af[tm], bf[tn], acc.t[tm][tn], 0, 0, 0);
  }
}

__device__ __forceinline__ float acc_sumsq(const AccW& acc) {
  float ss = 0.f;
#pragma unroll
  for (int tm = 0; tm < 2; tm++)
#pragma unroll
    for (int tn = 0; tn < 2; tn++)
#pragma unroll
      for (int i = 0; i < 4; i++) {
        float v = acc.t[tm][tn][i];
        ss += v * v;
      }
  return ss;
}

// Write acc into bounce LDS (stride HP). transposed -> buffer row = col index.
// C/D layout (m89): row = quad*4 + reg, col = lane&15 per 16x16 tile.
__device__ __forceinline__ void bounce_store(u16* Lb, const AccW& acc, float scale,
                                             bool transposed) {
  const int tid = threadIdx.x;
  const int wid = tid >> 6, lane = tid & 63;
  const int wm = (wid >> 2) * 32, wn = (wid & 3) * 32;
  const int l16 = lane & 15, quad = lane >> 4;
#pragma unroll
  for (int tm = 0; tm < 2; tm++)
#pragma unroll
    for (int tn = 0; tn < 2; tn++)
#pragma unroll
      for (int i = 0; i < 4; i++) {
        int r = wm + tm * 16 + quad * 4 + i;
        int c = wn + tn * 16 + l16;
        int key = transposed ? c : r, sec = transposed ? r : c;
        Lb[key * HP + sec] = f2b(acc.t[tm][tn][i] * scale);
      }
}

// 1024 threads: copy bounce LDS -> global, fully coalesced uint4.
__device__ __forceinline__ void copy_out(const u16* Lb, u16* out) {
  const int tid = threadIdx.x;
#pragma unroll
  for (int i = 0; i < 2; i++) {
    int g8 = tid + i * 1024;  // 0..2047 uint4 units
    int row = g8 >> 4, c8 = g8 & 15;
    *(uint4*)(out + g8 * 8) = *(const uint4*)(Lb + row * HP + c8 * 8);
  }
}

__device__ __forceinline__ float block_sum(float v, float* red, int nw) {
#pragma unroll
  for (int off = 32; off > 0; off >>= 1) v += __shfl_down(v, off);
  int wid = threadIdx.x >> 6;
  if ((threadIdx.x & 63) == 0) red[wid] = v;
  __syncthreads();
  if (threadIdx.x == 0) {
    float s = 0.f;
    for (int w = 0; w < nw; w++) s += red[w];
    red[0] = s;
  }
  __syncthreads();
  float s = red[0];
  __syncthreads();
  return s;
}

// ---------------- k1: one round-1 basis product per block ----------------
__global__ __launch_bounds__(1024, 8) void k1(const float* __restrict__ cores,
                                              u16* __restrict__ T) {
  __shared__ u16 Ald[128 * HP], Bld[128 * HP];
  const int j = blockIdx.x;       // 0..126 -> cores (2j+1, 2j+2)
  const int pq = blockIdx.y;      // 0:A0B0 1:A0B1 2:A1B0 3:A1B1 (coeff 1,b,a,ab)
  const int p = pq >> 1, q = pq & 1;
  const float* c1 = cores + (size_t)(2 * j + 1) * 32768;
  const float* c2 = cores + (size_t)(2 * j + 2) * 32768;
  const int tid = threadIdx.x;
#pragma unroll 4
  for (int i = 0; i < 16; i++) {
    int lh = tid + i * 1024;
    int l = lh >> 7, h = lh & 127;
    float a0 = c1[(l * 2 + 0) * 128 + h];
    float av = p ? (c1[(l * 2 + 1) * 128 + h] - a0) : a0;
    Ald[l * HP + h] = f2b(av);
    float b0 = c2[(l * 2 + 0) * 128 + h];
    float bv = q ? (c2[(l * 2 + 1) * 128 + h] - b0) : b0;
    Bld[h * HP + l] = f2b(bv);  // B basis transposed in LDS
  }
  __syncthreads();
  AccW acc;
  mfma_w16(Ald, Bld, acc);
  __syncthreads();  // A/B dead, reuse Ald as bounce
  const bool tr = (j % 2) == 0;  // even -> consumed as B operand -> store C^T
  bounce_store(Ald, acc, 1.f, tr);
  __syncthreads();
  copy_out(Ald, T + ((size_t)j * 4 + pq) * 16384);
}

// ---------------- k1b: round-2 basis TT_t = T1_p @ T2_q ----------------
__global__ __launch_bounds__(1024, 8) void k1b(const u16* __restrict__ T,
                                               u16* __restrict__ TT) {
  __shared__ u16 Ald[128 * HP], Bld[128 * HP];
  const int t = blockIdx.x;   // 0..15 : p = t>>2, q = t&3
  const int j2 = blockIdx.y;  // 0..62
  const int m1 = 2 * j2 + 1, m2 = 2 * j2 + 2;
  const u16* TA = T + ((size_t)m1 * 4 + (t >> 2)) * 16384;  // odd -> row-major
  const u16* TB = T + ((size_t)m2 * 4 + (t & 3)) * 16384;   // even -> [n][k] flat
  const int tid = threadIdx.x;
#pragma unroll
  for (int i = 0; i < 2; i++) {
    int g8 = tid + i * 1024;
    int r = g8 >> 4, c8 = g8 & 15;
    *(uint4*)(Ald + r * HP + c8 * 8) = *(const uint4*)(TA + g8 * 8);
    *(uint4*)(Bld + r * HP + c8 * 8) = *(const uint4*)(TB + g8 * 8);
  }
  __syncthreads();
  AccW acc;
  mfma_w16(Ald, Bld, acc);
  __syncthreads();
  bounce_store(Ald, acc, 1.f, (j2 % 2) == 0);
  __syncthreads();
  copy_out(Ald, TT + ((size_t)j2 * 16 + t) * 16384);
}

// ---------------- k1c: Gram partials G[j2][kc] = V V^T over K-chunk ----------
__global__ __launch_bounds__(256) void k1c(const u16* __restrict__ TT,
                                           float* __restrict__ Gpart) {
  __shared__ float Gp[1024];
  const int j2 = blockIdx.x, kc = blockIdx.y;
  const int tid = threadIdx.x;
  const int w = tid >> 6, lane = tid & 63;
  const int l16 = lane & 15, quad = lane >> 4;
  const u16* V = TT + (size_t)j2 * 16 * 16384 + (size_t)l16 * 16384;
  const int k0 = kc * 4096 + w * 1024;
  f32x4 acc = (f32x4){0.f, 0.f, 0.f, 0.f};
  for (int kk = k0; kk < k0 + 1024; kk += 32) {
    short8 av = *(const short8*)(V + kk + quad * 8);
    acc = __builtin_amdgcn_mfma_f32_16x16x32_bf16(av, av, acc, 0, 0, 0);
  }
#pragma unroll
  for (int i = 0; i < 4; i++)
    Gp[w * 256 + (quad * 4 + i) * 16 + l16] = acc[i];
  __syncthreads();
  Gpart[((size_t)j2 * 4 + kc) * 256 + tid] =
      Gp[tid] + Gp[256 + tid] + Gp[512 + tid] + Gp[768 + tid];
}

// ---------------- k2ns: coeffs/norms/logs (x<63) + special chain (x>=63) ------
__global__ __launch_bounds__(128) void k2ns(const float* __restrict__ x,
                                            const float* __restrict__ Gpart,
                                            const float* __restrict__ core0,
                                            const float* __restrict__ cores,
                                            const u16* __restrict__ T,
                                            float* __restrict__ cbuf,
                                            float* __restrict__ invn,
                                            float* __restrict__ sA,
                                            float* __restrict__ logs) {
  __shared__ float Gs[256];
  __shared__ float svec[128];
  __shared__ float red[8];
  const int bx = blockIdx.x, tid = threadIdx.x;
  if (bx < 63) {
    const int j2 = bx;
#pragma unroll
    for (int i = 0; i < 2; i++) {
      int t2 = tid + i * 128;
      float s = 0.f;
#pragma unroll
      for (int kc = 0; kc < 4; kc++)
        s += Gpart[((size_t)j2 * 4 + kc) * 256 + t2];
      Gs[t2] = s;
    }
    __syncthreads();
    if (tid < 64) {
      const int b = tid;
      const float* xb = x + b * 256;
      const int m1 = 2 * j2 + 1, m2 = 2 * j2 + 2;
      float a1 = xb[2 * m1 + 2], b1 = xb[2 * m1 + 3];
      float a2 = xb[2 * m2 + 2], b2 = xb[2 * m2 + 3];
      float c1[4] = {1.f, b1, a1, a1 * b1};
      float c2[4] = {1.f, b2, a2, a2 * b2};
      float c[16];
#pragma unroll
      for (int p = 0; p < 4; p++)
#pragma unroll
        for (int q = 0; q < 4; q++) c[p * 4 + q] = c1[p] * c2[q];
      float n2 = 0.f;
#pragma unroll
      for (int t = 0; t < 16; t++) {
        float s = 0.f;
#pragma unroll
        for (int u = 0; u < 16; u++) s += Gs[t * 16 + u] * c[u];
        n2 += c[t] * s;
      }
      float n = fmaxf(sqrtf(n2), 1e-12f);
      logs[b * 127 + 1 + j2] = logf(n);
      invn[j2 * 64 + b] = 1.f / n;
#pragma unroll
      for (int t = 0; t < 16; t++) cbuf[((size_t)j2 * 64 + b) * 16 + t] = c[t];
    }
  } else {
    const int b = bx - 63;
    const float* xb = x + b * 256;
    float x0 = xb[0], x1 = xb[1];
    svec[tid] = core0[tid] * (1.f - x0) + core0[128 + tid] * x0;
    __syncthreads();
    float acc1 = 0.f;
    for (int k = 0; k < 128; k++) {
      float m0 = cores[(k * 2 + 0) * 128 + tid];
      float m1 = cores[(k * 2 + 1) * 128 + tid];
      acc1 += svec[k] * (m0 + x1 * (m1 - m0));
    }
    float tot = block_sum(acc1 * acc1, red, 2);
    float n1 = fmaxf(sqrtf(tot), 1e-12f);
    float ln = logf(n1);
    svec[tid] = acc1 / n1;
    __syncthreads();
    float a = xb[2], bb = xb[3], ab = a * bb;
    float acc2 = 0.f;
    for (int k8 = 0; k8 < 16; k8++) {
      union { uint4 v; u16 s[8]; } q00, q01, q10, q11;
      q00.v = *(const uint4*)(T + tid * 128 + k8 * 8);
      q01.v = *(const uint4*)(T + 16384 + tid * 128 + k8 * 8);
      q10.v = *(const uint4*)(T + 32768 + tid * 128 + k8 * 8);
      q11.v = *(const uint4*)(T + 49152 + tid * 128 + k8 * 8);
#pragma unroll
      for (int e = 0; e < 8; e++) {
        float pk = b2f(q00.s[e]) + a * b2f(q10.s[e]) + bb * b2f(q01.s[e]) +
                   ab * b2f(q11.s[e]);
        acc2 += svec[k8 * 8 + e] * pk;
      }
    }
    float tot2 = block_sum(acc2 * acc2, red, 2);
    float n2 = fmaxf(sqrtf(tot2), 1e-12f);
    sA[b * 128 + tid] = acc2 / n2;
    if (tid == 0) logs[b * 127 + 0] = ln + logf(n2);
  }
}

// ---------------- k2c: element-wise combine, batch-split z=8 ----------------
__global__ __launch_bounds__(256) void k2c(const u16* __restrict__ TT,
                                           const float* __restrict__ cbuf,
                                           const float* __restrict__ invn,
                                           u16* __restrict__ M0) {
  const int slice = blockIdx.x;  // 0..15, 1024 elems each
  const int j2 = blockIdx.y;
  const int bz = blockIdx.z;     // 0..7, 8 batches each
  const int tid = threadIdx.x;
  const int e0 = slice * 1024 + tid * 4;
  float v[16][4];
#pragma unroll
  for (int t = 0; t < 16; t++) {
    union { uint2 u; u16 s[4]; } q;
    q.u = *(const uint2*)(TT + ((size_t)j2 * 16 + t) * 16384 + e0);
#pragma unroll
    for (int i = 0; i < 4; i++) v[t][i] = b2f(q.s[i]);
  }
  const float* cb0 = cbuf + (size_t)j2 * 64 * 16;
  const float* in0 = invn + (size_t)j2 * 64;
  u16* out = M0 + (size_t)j2 * 16384 + e0;
  for (int b = bz * 8; b < bz * 8 + 8; b++) {
    const float* cb = cb0 + b * 16;
    float inv = in0[b];
    float o[4] = {0.f, 0.f, 0.f, 0.f};
#pragma unroll
    for (int t = 0; t < 16; t++) {
      float ct = cb[t];
#pragma unroll
      for (int i = 0; i < 4; i++) o[i] += ct * v[t][i];
    }
    union { uint2 u; u16 s[4]; } r;
#pragma unroll
    for (int i = 0; i < 4; i++) r.s[i] = f2b(o[i] * inv);
    *(uint2*)(out + (size_t)b * 63 * 16384) = r.u;
  }
}

// ---------------- R3..R6: pairwise round (1024 threads) ----------------
__global__ __launch_bounds__(1024, 8) void roundk(const u16* __restrict__ In,
                                                  u16* __restrict__ Out,
                                                  const float* __restrict__ sIn,
                                                  float* __restrict__ sOut,
                                                  float* __restrict__ logs,
                                                  int count_in, int slot0) {
  __shared__ u16 Ald[128 * HP], Bld[128 * HP];
  __shared__ float red[16];
  const int b = blockIdx.y, p = blockIdx.x, tid = threadIdx.x;

  if (p == 0) {
    float* svec = (float*)Ald;
    if (tid < 128) svec[tid] = sIn[b * 128 + tid];
    __syncthreads();
    const u16* M = In + (size_t)b * count_in * 16384;  // In[b][0], transposed
    float acc = 0.f;
    if (tid < 128) {
      for (int k8 = 0; k8 < 16; k8++) {
        union { uint4 v; u16 s[8]; } q;
        q.v = *(const uint4*)(M + tid * 128 + k8 * 8);
#pragma unroll
        for (int e = 0; e < 8; e++) acc += svec[k8 * 8 + e] * b2f(q.s[e]);
      }
    }
    float tot = block_sum((tid < 128) ? acc * acc : 0.f, red, 16);
    float n = fmaxf(sqrtf(tot), 1e-12f);
    if (tid < 128) sOut[b * 128 + tid] = acc / n;
    if (tid == 0) logs[b * 127 + slot0] = logf(n);
  } else {
    const u16* A = In + ((size_t)b * count_in + (2 * p - 1)) * 16384;
    const u16* Bm = In + ((size_t)b * count_in + (2 * p)) * 16384;
#pragma unroll
    for (int i = 0; i < 2; i++) {
      int g8 = tid + i * 1024;
      int r = g8 >> 4, c8 = g8 & 15;
      *(uint4*)(Ald + r * HP + c8 * 8) = *(const uint4*)(A + g8 * 8);
      *(uint4*)(Bld + r * HP + c8 * 8) = *(const uint4*)(Bm + g8 * 8);
    }
    __syncthreads();
    AccW acc;
    mfma_w16(Ald, Bld, acc);
    float tot = block_sum(acc_sumsq(acc), red, 16);
    float n = fmaxf(sqrtf(tot), 1e-12f);
    if (tid == 0) logs[b * 127 + slot0 + p] = logf(n);
    int m = p - 1;
    int count_out = (count_in - 1) / 2;
    bounce_store(Ald, acc, 1.f / n, (m % 2) == 0);  // block_sum ended w/ barrier
    __syncthreads();
    copy_out(Ald, Out + ((size_t)b * count_out + m) * 16384);
  }
}

// ---------------- r7f: R7 + R8 + logits, one block per batch ----------------
__global__ __launch_bounds__(1024, 8) void r7f(const u16* __restrict__ In,
                                               const float* __restrict__ sIn,
                                               const float* __restrict__ logs,
                                               const float* __restrict__ cls,
                                               float* __restrict__ out) {
  __shared__ u16 Ald[128 * HP], Bld[128 * HP];
  __shared__ float svec[128], ovec[128], red[16];
  const int b = blockIdx.x, tid = threadIdx.x;
  if (tid < 128) svec[tid] = sIn[b * 128 + tid];
  const u16* A = In + ((size_t)b * 3 + 1) * 16384;   // row-major
  const u16* Bm = In + ((size_t)b * 3 + 2) * 16384;  // transposed
#pragma unroll
  for (int i = 0; i < 2; i++) {
    int g8 = tid + i * 1024;
    int r = g8 >> 4, c8 = g8 & 15;
    *(uint4*)(Ald + r * HP + c8 * 8) = *(const uint4*)(A + g8 * 8);
    *(uint4*)(Bld + r * HP + c8 * 8) = *(const uint4*)(Bm + g8 * 8);
  }
  __syncthreads();
  AccW acc;
  mfma_w16(Ald, Bld, acc);
  float tot = block_sum(acc_sumsq(acc), red, 16);
  float n1 = fmaxf(sqrtf(tot), 1e-12f);
  float lg = logf(n1);
  // C (normalized) -> bounce LDS transposed: Lb[c*HP + r]
  bounce_store(Ald, acc, 1.f / n1, true);
  // special dot with In[b*3+0] (global, transposed layout)
  const u16* M0p = In + (size_t)b * 3 * 16384;
  float acc0 = 0.f;
  if (tid < 128) {
    for (int k8 = 0; k8 < 16; k8++) {
      union { uint4 v; u16 s[8]; } q;
      q.v = *(const uint4*)(M0p + tid * 128 + k8 * 8);
#pragma unroll
      for (int e = 0; e < 8; e++) acc0 += svec[k8 * 8 + e] * b2f(q.s[e]);
    }
  }
  float tot0 = block_sum((tid < 128) ? acc0 * acc0 : 0.f, red, 16);
  float n0 = fmaxf(sqrtf(tot0), 1e-12f);
  lg += logf(n0);
  if (tid < 128) ovec[tid] = acc0 / n0;
  __syncthreads();
  // R8: res[c] = sum_r ovec[r] * C[r][c]  (C in Ald as [c][r])
  float acc2 = 0.f;
  if (tid < 128) {
    for (int r = 0; r < 128; r++) acc2 += ovec[r] * b2f(Ald[tid * HP + r]);
  }
  float tot2 = block_sum((tid < 128) ? acc2 * acc2 : 0.f, red, 16);
  float n2 = fmaxf(sqrtf(tot2), 1e-12f);
  lg += logf(n2);
  if (tid < 128) svec[tid] = acc2 / n2;
  __syncthreads();
  if (tid < 10) {
    float a = 0.f;
    for (int h = 0; h < 128; h++) a += svec[h] * cls[tid * 128 + h];
    float L = lg;
    for (int i = 0; i < 124; i++) L += logs[b * 127 + i];
    out[b * 10 + tid] = a + L;
  }
}

extern "C" void kernel_launch(void* const* d_in, const int* in_sizes, int n_in,
                              void* d_out, int out_size, void* d_ws, size_t ws_size,
                              hipStream_t stream) {
  (void)in_sizes; (void)n_in; (void)out_size; (void)ws_size;
  const float* x     = (const float*)d_in[0];  // (64,256)
  const float* core0 = (const float*)d_in[1];  // (1,2,128)
  const float* cores = (const float*)d_in[2];  // (255,128,2,128)
  const float* cls   = (const float*)d_in[3];  // (10,128)
  float* out = (float*)d_out;
  char* ws = (char*)d_ws;

  // Region A (65 MB): early = T (16.6 MB) + TT (33 MB); later reused as M1.
  constexpr size_t SZ_T  = (size_t)127 * 4 * 16384 * 2;   //  16,646,144
  constexpr size_t SZ_A  = (size_t)64 * 31 * 16384 * 2;   //  65,011,712 (M1)
  constexpr size_t SZ_M0 = (size_t)64 * 63 * 16384 * 2;   // 132,120,576

  u16*   T    = (u16*)(ws);
  u16*   TT   = (u16*)(ws + SZ_T);
  u16*   M1   = (u16*)(ws);            // aliases T+TT after k2c completes
  u16*   M0   = (u16*)(ws + SZ_A);
  char*  tail0 = ws + SZ_A + SZ_M0;
  float* Gpart = (float*)(tail0);                      // 63*4*256*4 = 258,048
  float* cbuf = (float*)(tail0 + 262144);              // 63*64*16*4 = 258,048
  float* invn = (float*)(tail0 + 262144 + 262144);     // 16,128
  float* sA   = (float*)(tail0 + 262144 + 262144 + 16384);
  float* sB   = (float*)(tail0 + 262144 + 262144 + 16384 + 32768);
  float* logs = (float*)(tail0 + 262144 + 262144 + 16384 + 65536);

  k1  <<<dim3(127, 4), 1024, 0, stream>>>(cores, T);
  k1b <<<dim3(16, 63), 1024, 0, stream>>>(T, TT);
  k1c <<<dim3(63, 4), 256, 0, stream>>>(TT, Gpart);
  k2ns<<<dim3(127), 128, 0, stream>>>(x, Gpart, core0, cores, T, cbuf, invn, sA,
                                      logs);
  k2c <<<dim3(16, 63, 8), 256, 0, stream>>>(TT, cbuf, invn, M0);
  // log slots: 0 special(r1+r2), 1..63 pairs(r1+r2), R3 64..95, R4 96..111,
  //            R5 112..119, R6 120..123; r7f computes 124..126 locally.
  roundk<<<dim3(32, 64), 1024, 0, stream>>>(M0, M1, sA, sB, logs, 63, 64);
  roundk<<<dim3(16, 64), 1024, 0, stream>>>(M1, M0, sB, sA, logs, 31, 96);
  roundk<<<dim3(8, 64),  1024, 0, stream>>>(M0, M1, sA, sB, logs, 15, 112);
  roundk<<<dim3(4, 64),  1024, 0, stream>>>(M1, M0, sB, sA, logs, 7, 120);
  r7f  <<<dim3(64), 1024, 0, stream>>>(M0, sA, logs, cls, out);
}

// Round 6
// 261.392 us; speedup vs baseline: 1.7349x; 1.0734x over previous
//
#include <hip/hip_runtime.h>
#include <stdint.h>

// MPS classifier forward, MI355X.
//   k1  : 127 blocks (4 LDS basis buffers, 139KB), all 4 round-1 products/block
//   k1b : (16,63) blocks, round-2 basis TT_t = T1_p @ T2_q  (batch-independent)
//   k1c : (63,4) blocks, Gram partials over K-chunks
//   k2ns: 127 blocks: x<63 -> coeffs/norms/logs; x>=63 -> special chain r1+r2
//   k2c : (16,63) element-wise combine M0 = (sum_t c_t TT_t)/n; TT slice in regs,
//         all 64 batches per block (single TT fetch), coeffs staged in LDS
//   R3..R6: pairwise rounds (roundk, 1024 thr, 16 waves)
//   r7f : R7 + R8 + logits fused, 64 blocks

typedef unsigned short u16;
typedef __attribute__((ext_vector_type(8))) short short8;
typedef __attribute__((ext_vector_type(4))) float f32x4;

#define HP 136  // LDS row stride in bf16: 272 B, 16B-aligned, 2-way-bank-free

__device__ __forceinline__ u16 f2b(float f) {
  uint32_t u = __builtin_bit_cast(uint32_t, f);
  u += 0x7FFFu + ((u >> 16) & 1u);
  return (u16)(u >> 16);
}
__device__ __forceinline__ float b2f(u16 b) {
  uint32_t u = ((uint32_t)b) << 16;
  return __builtin_bit_cast(float, u);
}

struct AccW { f32x4 t[2][2]; };  // 16-wave config: 32x32 wave tile

// 1024-thread (16-wave) 128x128x128. A: [m][k] LDS, B: [n][k] LDS.
__device__ __forceinline__ void mfma_w16(const u16* Alds, const u16* Blds,
                                         AccW& acc) {
  const int tid = threadIdx.x;
  const int wid = tid >> 6, lane = tid & 63;
  const int wm = (wid >> 2) * 32, wn = (wid & 3) * 32;
  const int l16 = lane & 15, quad = lane >> 4;
#pragma unroll
  for (int tm = 0; tm < 2; tm++)
#pragma unroll
    for (int tn = 0; tn < 2; tn++)
      acc.t[tm][tn] = (f32x4){0.f, 0.f, 0.f, 0.f};
#pragma unroll
  for (int kk = 0; kk < 128; kk += 32) {
    short8 af[2], bf[2];
#pragma unroll
    for (int t = 0; t < 2; t++) {
      af[t] = *(const short8*)(Alds + (wm + t * 16 + l16) * HP + kk + quad * 8);
      bf[t] = *(const short8*)(Blds + (wn + t * 16 + l16) * HP + kk + quad * 8);
    }
#pragma unroll
    for (int tm = 0; tm < 2; tm++)
#pragma unroll
      for (int tn = 0; tn < 2; tn++)
        acc.t[tm][tn] = __builtin_amdgcn_mfma_f32_16x16x32_bf16(
            af[tm], bf[tn], acc.t[tm][tn], 0, 0, 0);
  }
}

__device__ __forceinline__ float acc_sumsq(const AccW& acc) {
  float ss = 0.f;
#pragma unroll
  for (int tm = 0; tm < 2; tm++)
#pragma unroll
    for (int tn = 0; tn < 2; tn++)
#pragma unroll
      for (int i = 0; i < 4; i++) {
        float v = acc.t[tm][tn][i];
        ss += v * v;
      }
  return ss;
}

// Write acc into bounce LDS (stride HP). transposed -> buffer row = col index.
// C/D layout (m89): row = quad*4 + reg, col = lane&15 per 16x16 tile.
__device__ __forceinline__ void bounce_store(u16* Lb, const AccW& acc, float scale,
                                             bool transposed) {
  const int tid = threadIdx.x;
  const int wid = tid >> 6, lane = tid & 63;
  const int wm = (wid >> 2) * 32, wn = (wid & 3) * 32;
  const int l16 = lane & 15, quad = lane >> 4;
#pragma unroll
  for (int tm = 0; tm < 2; tm++)
#pragma unroll
    for (int tn = 0; tn < 2; tn++)
#pragma unroll
      for (int i = 0; i < 4; i++) {
        int r = wm + tm * 16 + quad * 4 + i;
        int c = wn + tn * 16 + l16;
        int key = transposed ? c : r, sec = transposed ? r : c;
        Lb[key * HP + sec] = f2b(acc.t[tm][tn][i] * scale);
      }
}

// 1024 threads: copy bounce LDS -> global, fully coalesced uint4.
__device__ __forceinline__ void copy_out(const u16* Lb, u16* out) {
  const int tid = threadIdx.x;
#pragma unroll
  for (int i = 0; i < 2; i++) {
    int g8 = tid + i * 1024;  // 0..2047 uint4 units
    int row = g8 >> 4, c8 = g8 & 15;
    *(uint4*)(out + g8 * 8) = *(const uint4*)(Lb + row * HP + c8 * 8);
  }
}

__device__ __forceinline__ float block_sum(float v, float* red, int nw) {
#pragma unroll
  for (int off = 32; off > 0; off >>= 1) v += __shfl_down(v, off);
  int wid = threadIdx.x >> 6;
  if ((threadIdx.x & 63) == 0) red[wid] = v;
  __syncthreads();
  if (threadIdx.x == 0) {
    float s = 0.f;
    for (int w = 0; w < nw; w++) s += red[w];
    red[0] = s;
  }
  __syncthreads();
  float s = red[0];
  __syncthreads();
  return s;
}

// ---------------- k1: all 4 round-1 basis products per block ----------------
__global__ __launch_bounds__(1024) void k1(const float* __restrict__ cores,
                                           u16* __restrict__ T) {
  __shared__ u16 A0[128 * HP], A1[128 * HP], B0[128 * HP], B1[128 * HP];
  const int j = blockIdx.x;  // 0..126 -> cores (2j+1, 2j+2)
  const float* c1 = cores + (size_t)(2 * j + 1) * 32768;
  const float* c2 = cores + (size_t)(2 * j + 2) * 32768;
  const int tid = threadIdx.x;
#pragma unroll 4
  for (int i = 0; i < 16; i++) {
    int lh = tid + i * 1024;
    int l = lh >> 7, h = lh & 127;
    float a0 = c1[(l * 2 + 0) * 128 + h];
    float a1 = c1[(l * 2 + 1) * 128 + h];
    A0[l * HP + h] = f2b(a0);
    A1[l * HP + h] = f2b(a1 - a0);
    float b0 = c2[(l * 2 + 0) * 128 + h];
    float b1 = c2[(l * 2 + 1) * 128 + h];
    B0[h * HP + l] = f2b(b0);  // B basis transposed in LDS
    B1[h * HP + l] = f2b(b1 - b0);
  }
  __syncthreads();
  const bool tr = (j % 2) == 0;  // even -> consumed as B operand -> store C^T
  u16* Tj = T + (size_t)j * 4 * 16384;
  AccW a00, a01, a10, a11;
  mfma_w16(A0, B0, a00);  // coeff 1
  mfma_w16(A0, B1, a01);  // coeff b
  __syncthreads();        // all waves done reading A0 -> reuse as bounce
  bounce_store(A0, a00, 1.f, tr); __syncthreads();
  copy_out(A0, Tj + 0 * 16384);   __syncthreads();
  bounce_store(A0, a01, 1.f, tr); __syncthreads();
  copy_out(A0, Tj + 1 * 16384);
  mfma_w16(A1, B0, a10);  // coeff a
  mfma_w16(A1, B1, a11);  // coeff ab
  __syncthreads();
  bounce_store(A0, a10, 1.f, tr); __syncthreads();
  copy_out(A0, Tj + 2 * 16384);   __syncthreads();
  bounce_store(A0, a11, 1.f, tr); __syncthreads();
  copy_out(A0, Tj + 3 * 16384);
}

// ---------------- k1b: round-2 basis TT_t = T1_p @ T2_q ----------------
__global__ __launch_bounds__(1024, 8) void k1b(const u16* __restrict__ T,
                                               u16* __restrict__ TT) {
  __shared__ u16 Ald[128 * HP], Bld[128 * HP];
  const int t = blockIdx.x;   // 0..15 : p = t>>2, q = t&3
  const int j2 = blockIdx.y;  // 0..62
  const int m1 = 2 * j2 + 1, m2 = 2 * j2 + 2;
  const u16* TA = T + ((size_t)m1 * 4 + (t >> 2)) * 16384;  // odd -> row-major
  const u16* TB = T + ((size_t)m2 * 4 + (t & 3)) * 16384;   // even -> [n][k] flat
  const int tid = threadIdx.x;
#pragma unroll
  for (int i = 0; i < 2; i++) {
    int g8 = tid + i * 1024;
    int r = g8 >> 4, c8 = g8 & 15;
    *(uint4*)(Ald + r * HP + c8 * 8) = *(const uint4*)(TA + g8 * 8);
    *(uint4*)(Bld + r * HP + c8 * 8) = *(const uint4*)(TB + g8 * 8);
  }
  __syncthreads();
  AccW acc;
  mfma_w16(Ald, Bld, acc);
  __syncthreads();
  bounce_store(Ald, acc, 1.f, (j2 % 2) == 0);
  __syncthreads();
  copy_out(Ald, TT + ((size_t)j2 * 16 + t) * 16384);
}

// ---------------- k1c: Gram partials G[j2][kc] = V V^T over K-chunk ----------
__global__ __launch_bounds__(256) void k1c(const u16* __restrict__ TT,
                                           float* __restrict__ Gpart) {
  __shared__ float Gp[1024];
  const int j2 = blockIdx.x, kc = blockIdx.y;
  const int tid = threadIdx.x;
  const int w = tid >> 6, lane = tid & 63;
  const int l16 = lane & 15, quad = lane >> 4;
  const u16* V = TT + (size_t)j2 * 16 * 16384 + (size_t)l16 * 16384;
  const int k0 = kc * 4096 + w * 1024;
  f32x4 acc = (f32x4){0.f, 0.f, 0.f, 0.f};
  for (int kk = k0; kk < k0 + 1024; kk += 32) {
    short8 av = *(const short8*)(V + kk + quad * 8);
    acc = __builtin_amdgcn_mfma_f32_16x16x32_bf16(av, av, acc, 0, 0, 0);
  }
#pragma unroll
  for (int i = 0; i < 4; i++)
    Gp[w * 256 + (quad * 4 + i) * 16 + l16] = acc[i];
  __syncthreads();
  Gpart[((size_t)j2 * 4 + kc) * 256 + tid] =
      Gp[tid] + Gp[256 + tid] + Gp[512 + tid] + Gp[768 + tid];
}

// ---------------- k2ns: coeffs/norms/logs (x<63) + special chain (x>=63) ------
__global__ __launch_bounds__(128) void k2ns(const float* __restrict__ x,
                                            const float* __restrict__ Gpart,
                                            const float* __restrict__ core0,
                                            const float* __restrict__ cores,
                                            const u16* __restrict__ T,
                                            float* __restrict__ cbuf,
                                            float* __restrict__ invn,
                                            float* __restrict__ sA,
                                            float* __restrict__ logs) {
  __shared__ float Gs[256];
  __shared__ float svec[128];
  __shared__ float red[8];
  const int bx = blockIdx.x, tid = threadIdx.x;
  if (bx < 63) {
    const int j2 = bx;
#pragma unroll
    for (int i = 0; i < 2; i++) {
      int t2 = tid + i * 128;
      float s = 0.f;
#pragma unroll
      for (int kc = 0; kc < 4; kc++)
        s += Gpart[((size_t)j2 * 4 + kc) * 256 + t2];
      Gs[t2] = s;
    }
    __syncthreads();
    if (tid < 64) {
      const int b = tid;
      const float* xb = x + b * 256;
      const int m1 = 2 * j2 + 1, m2 = 2 * j2 + 2;
      float a1 = xb[2 * m1 + 2], b1 = xb[2 * m1 + 3];
      float a2 = xb[2 * m2 + 2], b2 = xb[2 * m2 + 3];
      float c1[4] = {1.f, b1, a1, a1 * b1};
      float c2[4] = {1.f, b2, a2, a2 * b2};
      float c[16];
#pragma unroll
      for (int p = 0; p < 4; p++)
#pragma unroll
        for (int q = 0; q < 4; q++) c[p * 4 + q] = c1[p] * c2[q];
      float n2 = 0.f;
#pragma unroll
      for (int t = 0; t < 16; t++) {
        float s = 0.f;
#pragma unroll
        for (int u = 0; u < 16; u++) s += Gs[t * 16 + u] * c[u];
        n2 += c[t] * s;
      }
      float n = fmaxf(sqrtf(n2), 1e-12f);
      logs[b * 127 + 1 + j2] = logf(n);
      invn[j2 * 64 + b] = 1.f / n;
#pragma unroll
      for (int t = 0; t < 16; t++) cbuf[((size_t)j2 * 64 + b) * 16 + t] = c[t];
    }
  } else {
    const int b = bx - 63;
    const float* xb = x + b * 256;
    float x0 = xb[0], x1 = xb[1];
    svec[tid] = core0[tid] * (1.f - x0) + core0[128 + tid] * x0;
    __syncthreads();
    float acc1 = 0.f;
    for (int k = 0; k < 128; k++) {
      float m0 = cores[(k * 2 + 0) * 128 + tid];
      float m1 = cores[(k * 2 + 1) * 128 + tid];
      acc1 += svec[k] * (m0 + x1 * (m1 - m0));
    }
    float tot = block_sum(acc1 * acc1, red, 2);
    float n1 = fmaxf(sqrtf(tot), 1e-12f);
    float ln = logf(n1);
    svec[tid] = acc1 / n1;
    __syncthreads();
    float a = xb[2], bb = xb[3], ab = a * bb;
    float acc2 = 0.f;
    for (int k8 = 0; k8 < 16; k8++) {
      union { uint4 v; u16 s[8]; } q00, q01, q10, q11;
      q00.v = *(const uint4*)(T + tid * 128 + k8 * 8);
      q01.v = *(const uint4*)(T + 16384 + tid * 128 + k8 * 8);
      q10.v = *(const uint4*)(T + 32768 + tid * 128 + k8 * 8);
      q11.v = *(const uint4*)(T + 49152 + tid * 128 + k8 * 8);
#pragma unroll
      for (int e = 0; e < 8; e++) {
        float pk = b2f(q00.s[e]) + a * b2f(q10.s[e]) + bb * b2f(q01.s[e]) +
                   ab * b2f(q11.s[e]);
        acc2 += svec[k8 * 8 + e] * pk;
      }
    }
    float tot2 = block_sum(acc2 * acc2, red, 2);
    float n2 = fmaxf(sqrtf(tot2), 1e-12f);
    sA[b * 128 + tid] = acc2 / n2;
    if (tid == 0) logs[b * 127 + 0] = ln + logf(n2);
  }
}

// ---------------- k2c: combine, single TT fetch, all 64 batches/block ----------
__global__ __launch_bounds__(256, 4) void k2c(const u16* __restrict__ TT,
                                              const float* __restrict__ cbuf,
                                              const float* __restrict__ invn,
                                              u16* __restrict__ M0) {
  __shared__ float cbS[1024];  // [b][t]
  __shared__ float invS[64];
  const int slice = blockIdx.x;  // 0..15, 1024 elems each
  const int j2 = blockIdx.y;
  const int tid = threadIdx.x;
  for (int i = tid; i < 1024; i += 256) cbS[i] = cbuf[(size_t)j2 * 1024 + i];
  if (tid < 64) invS[tid] = invn[j2 * 64 + tid];
  const int e0 = slice * 1024 + tid * 4;
  float v[16][4];
#pragma unroll
  for (int t = 0; t < 16; t++) {
    union { uint2 u; u16 s[4]; } q;
    q.u = *(const uint2*)(TT + ((size_t)j2 * 16 + t) * 16384 + e0);
#pragma unroll
    for (int i = 0; i < 4; i++) v[t][i] = b2f(q.s[i]);
  }
  __syncthreads();
  u16* out = M0 + (size_t)j2 * 16384 + e0;
#pragma unroll 2
  for (int b = 0; b < 64; b++) {
    const float* cb = cbS + b * 16;
    float inv = invS[b];
    float o[4] = {0.f, 0.f, 0.f, 0.f};
#pragma unroll
    for (int t = 0; t < 16; t++) {
      float ct = cb[t];
#pragma unroll
      for (int i = 0; i < 4; i++) o[i] += ct * v[t][i];
    }
    union { uint2 u; u16 s[4]; } r;
#pragma unroll
    for (int i = 0; i < 4; i++) r.s[i] = f2b(o[i] * inv);
    *(uint2*)(out + (size_t)b * 63 * 16384) = r.u;
  }
}

// ---------------- R3..R6: pairwise round (1024 threads) ----------------
__global__ __launch_bounds__(1024, 8) void roundk(const u16* __restrict__ In,
                                                  u16* __restrict__ Out,
                                                  const float* __restrict__ sIn,
                                                  float* __restrict__ sOut,
                                                  float* __restrict__ logs,
                                                  int count_in, int slot0) {
  __shared__ u16 Ald[128 * HP], Bld[128 * HP];
  __shared__ float red[16];
  const int b = blockIdx.y, p = blockIdx.x, tid = threadIdx.x;

  if (p == 0) {
    float* svec = (float*)Ald;
    if (tid < 128) svec[tid] = sIn[b * 128 + tid];
    __syncthreads();
    const u16* M = In + (size_t)b * count_in * 16384;  // In[b][0], transposed
    float acc = 0.f;
    if (tid < 128) {
      for (int k8 = 0; k8 < 16; k8++) {
        union { uint4 v; u16 s[8]; } q;
        q.v = *(const uint4*)(M + tid * 128 + k8 * 8);
#pragma unroll
        for (int e = 0; e < 8; e++) acc += svec[k8 * 8 + e] * b2f(q.s[e]);
      }
    }
    float tot = block_sum((tid < 128) ? acc * acc : 0.f, red, 16);
    float n = fmaxf(sqrtf(tot), 1e-12f);
    if (tid < 128) sOut[b * 128 + tid] = acc / n;
    if (tid == 0) logs[b * 127 + slot0] = logf(n);
  } else {
    const u16* A = In + ((size_t)b * count_in + (2 * p - 1)) * 16384;
    const u16* Bm = In + ((size_t)b * count_in + (2 * p)) * 16384;
#pragma unroll
    for (int i = 0; i < 2; i++) {
      int g8 = tid + i * 1024;
      int r = g8 >> 4, c8 = g8 & 15;
      *(uint4*)(Ald + r * HP + c8 * 8) = *(const uint4*)(A + g8 * 8);
      *(uint4*)(Bld + r * HP + c8 * 8) = *(const uint4*)(Bm + g8 * 8);
    }
    __syncthreads();
    AccW acc;
    mfma_w16(Ald, Bld, acc);
    float tot = block_sum(acc_sumsq(acc), red, 16);
    float n = fmaxf(sqrtf(tot), 1e-12f);
    if (tid == 0) logs[b * 127 + slot0 + p] = logf(n);
    int m = p - 1;
    int count_out = (count_in - 1) / 2;
    bounce_store(Ald, acc, 1.f / n, (m % 2) == 0);  // block_sum ended w/ barrier
    __syncthreads();
    copy_out(Ald, Out + ((size_t)b * count_out + m) * 16384);
  }
}

// ---------------- r7f: R7 + R8 + logits, one block per batch ----------------
__global__ __launch_bounds__(1024, 8) void r7f(const u16* __restrict__ In,
                                               const float* __restrict__ sIn,
                                               const float* __restrict__ logs,
                                               const float* __restrict__ cls,
                                               float* __restrict__ out) {
  __shared__ u16 Ald[128 * HP], Bld[128 * HP];
  __shared__ float svec[128], ovec[128], red[16];
  const int b = blockIdx.x, tid = threadIdx.x;
  if (tid < 128) svec[tid] = sIn[b * 128 + tid];
  const u16* A = In + ((size_t)b * 3 + 1) * 16384;   // row-major
  const u16* Bm = In + ((size_t)b * 3 + 2) * 16384;  // transposed
#pragma unroll
  for (int i = 0; i < 2; i++) {
    int g8 = tid + i * 1024;
    int r = g8 >> 4, c8 = g8 & 15;
    *(uint4*)(Ald + r * HP + c8 * 8) = *(const uint4*)(A + g8 * 8);
    *(uint4*)(Bld + r * HP + c8 * 8) = *(const uint4*)(Bm + g8 * 8);
  }
  __syncthreads();
  AccW acc;
  mfma_w16(Ald, Bld, acc);
  float tot = block_sum(acc_sumsq(acc), red, 16);
  float n1 = fmaxf(sqrtf(tot), 1e-12f);
  float lg = logf(n1);
  // C (normalized) -> bounce LDS transposed: Lb[c*HP + r]
  bounce_store(Ald, acc, 1.f / n1, true);
  // special dot with In[b*3+0] (global, transposed layout)
  const u16* M0p = In + (size_t)b * 3 * 16384;
  float acc0 = 0.f;
  if (tid < 128) {
    for (int k8 = 0; k8 < 16; k8++) {
      union { uint4 v; u16 s[8]; } q;
      q.v = *(const uint4*)(M0p + tid * 128 + k8 * 8);
#pragma unroll
      for (int e = 0; e < 8; e++) acc0 += svec[k8 * 8 + e] * b2f(q.s[e]);
    }
  }
  float tot0 = block_sum((tid < 128) ? acc0 * acc0 : 0.f, red, 16);
  float n0 = fmaxf(sqrtf(tot0), 1e-12f);
  lg += logf(n0);
  if (tid < 128) ovec[tid] = acc0 / n0;
  __syncthreads();
  // R8: res[c] = sum_r ovec[r] * C[r][c]  (C in Ald as [c][r])
  float acc2 = 0.f;
  if (tid < 128) {
    for (int r = 0; r < 128; r++) acc2 += ovec[r] * b2f(Ald[tid * HP + r]);
  }
  float tot2 = block_sum((tid < 128) ? acc2 * acc2 : 0.f, red, 16);
  float n2 = fmaxf(sqrtf(tot2), 1e-12f);
  lg += logf(n2);
  if (tid < 128) svec[tid] = acc2 / n2;
  __syncthreads();
  if (tid < 10) {
    float a = 0.f;
    for (int h = 0; h < 128; h++) a += svec[h] * cls[tid * 128 + h];
    float L = lg;
    for (int i = 0; i < 124; i++) L += logs[b * 127 + i];
    out[b * 10 + tid] = a + L;
  }
}

extern "C" void kernel_launch(void* const* d_in, const int* in_sizes, int n_in,
                              void* d_out, int out_size, void* d_ws, size_t ws_size,
                              hipStream_t stream) {
  (void)in_sizes; (void)n_in; (void)out_size; (void)ws_size;
  const float* x     = (const float*)d_in[0];  // (64,256)
  const float* core0 = (const float*)d_in[1];  // (1,2,128)
  const float* cores = (const float*)d_in[2];  // (255,128,2,128)
  const float* cls   = (const float*)d_in[3];  // (10,128)
  float* out = (float*)d_out;
  char* ws = (char*)d_ws;

  // Region A (65 MB): early = T (16.6 MB) + TT (33 MB); later reused as M1.
  constexpr size_t SZ_T  = (size_t)127 * 4 * 16384 * 2;   //  16,646,144
  constexpr size_t SZ_A  = (size_t)64 * 31 * 16384 * 2;   //  65,011,712 (M1)
  constexpr size_t SZ_M0 = (size_t)64 * 63 * 16384 * 2;   // 132,120,576

  u16*   T    = (u16*)(ws);
  u16*   TT   = (u16*)(ws + SZ_T);
  u16*   M1   = (u16*)(ws);            // aliases T+TT after k2c completes
  u16*   M0   = (u16*)(ws + SZ_A);
  char*  tail0 = ws + SZ_A + SZ_M0;
  float* Gpart = (float*)(tail0);                      // 63*4*256*4 = 258,048
  float* cbuf = (float*)(tail0 + 262144);              // 63*64*16*4 = 258,048
  float* invn = (float*)(tail0 + 262144 + 262144);     // 16,128
  float* sA   = (float*)(tail0 + 262144 + 262144 + 16384);
  float* sB   = (float*)(tail0 + 262144 + 262144 + 16384 + 32768);
  float* logs = (float*)(tail0 + 262144 + 262144 + 16384 + 65536);

  k1  <<<dim3(127), 1024, 0, stream>>>(cores, T);
  k1b <<<dim3(16, 63), 1024, 0, stream>>>(T, TT);
  k1c <<<dim3(63, 4), 256, 0, stream>>>(TT, Gpart);
  k2ns<<<dim3(127), 128, 0, stream>>>(x, Gpart, core0, cores, T, cbuf, invn, sA,
                                      logs);
  k2c <<<dim3(16, 63), 256, 0, stream>>>(TT, cbuf, invn, M0);
  // log slots: 0 special(r1+r2), 1..63 pairs(r1+r2), R3 64..95, R4 96..111,
  //            R5 112..119, R6 120..123; r7f computes 124..126 locally.
  roundk<<<dim3(32, 64), 1024, 0, stream>>>(M0, M1, sA, sB, logs, 63, 64);
  roundk<<<dim3(16, 64), 1024, 0, stream>>>(M1, M0, sB, sA, logs, 31, 96);
  roundk<<<dim3(8, 64),  1024, 0, stream>>>(M0, M1, sA, sB, logs, 15, 112);
  roundk<<<dim3(4, 64),  1024, 0, stream>>>(M1, M0, sB, sA, logs, 7, 120);
  r7f  <<<dim3(64), 1024, 0, stream>>>(M0, sA, logs, cls, out);
}